// Round 3
// baseline (12834.485 us; speedup 1.0000x reference)
//
#include <hip/hip_runtime.h>
#include <hip/hip_bf16.h>
#include <math.h>

// ---------------------------------------------------------------------------
// DeepLoc model on MI355X.  B=128, L=1000, E=32, conv branches K={1,3,5,9,15,21}
// NF=20 -> 120ch, conv2 -> 128ch, BiLSTM H=256/dir, decoder LSTMCell H=512,
// attention over L, 10 decoder steps, fc 512 -> out 8 (sigmoid).
//
// R2 -> R3 changes (R2: passed, 10.43 ms, k_lstm 8.5 ms w/ FETCH 761 MB):
//  * k_lstm: h-exchange + barrier via RELAXED agent-scope atomics (sc0/sc1 ->
//    Infinity-Cache coherent, NO L2 invalidate/writeback per step). The old
//    ACQUIRE/RELEASE + __threadfence nuked L2 every step -> 761 MB HBM refetch.
//    seq stays in normal cached loads (L2-resident now).
//  * k_softmax_ctx: 512 thr, thread-per-h, l-outer coalesced ctx reduction
//    (was column-strided 1KB-stride scalar loads, L2-thrashing).
//  * e_enc layout flipped to [n][B*L]; k_score lanes now read consecutive l.
// ---------------------------------------------------------------------------

typedef __bf16 bf16_t;
typedef __bf16 bf16x8 __attribute__((ext_vector_type(8)));
typedef float f32x4 __attribute__((ext_vector_type(4)));

__device__ __constant__ int KBS[6]  = {1, 3, 5, 9, 15, 21};
__device__ __constant__ int WOFF[6] = {0, 1024, 4096, 9216, 18432, 33792}; // elem offsets (1024*K cum)

__device__ inline f32x4 mfma16(bf16x8 a, bf16x8 b, f32x4 c) {
  return __builtin_amdgcn_mfma_f32_16x16x32_bf16(a, b, c, 0, 0, 0);
}
__device__ inline float sigm(float x) { return 1.f / (1.f + __expf(-x)); }
__device__ inline float tanh_fast(float x) {
  x = fminf(15.f, fmaxf(-15.f, x));
  float e = __expf(2.f * x);
  return (e - 1.f) / (e + 1.f);
}

// device-coherent (IC) accessors: relaxed agent atomics -> sc0 sc1, no cache inv
__device__ inline void store_h_ic(bf16_t* p, bf16_t v) {
  unsigned short b = __builtin_bit_cast(unsigned short, v);
  __hip_atomic_store((unsigned short*)p, b, __ATOMIC_RELAXED, __HIP_MEMORY_SCOPE_AGENT);
}
__device__ inline bf16x8 load_h_ic8(const bf16_t* p) {
  const unsigned* q = (const unsigned*)p;
  union { unsigned u[4]; bf16x8 v; } r;
#pragma unroll
  for (int i = 0; i < 4; ++i)
    r.u[i] = __hip_atomic_load(q + i, __ATOMIC_RELAXED, __HIP_MEMORY_SCOPE_AGENT);
  return r.v;
}

// ---------------------------------------------------------------------------
// init: zero h (IC-coherent)/barriers/pads, dec_in = [c0 | 0], cbias concat
// ---------------------------------------------------------------------------
__global__ void k_init(bf16_t* hbuf, unsigned* bar, bf16_t* feat1p, float* cd,
                       bf16_t* dec_in, float* cbias, const float* c0,
                       const float* cb0, const float* cb1, const float* cb2,
                       const float* cb3, const float* cb4, const float* cb5) {
  int i = blockIdx.x * 256 + threadIdx.x;
  if (i < 65536) {  // hbuf zeros, through IC so sc1 readers see them
    __hip_atomic_store((unsigned*)hbuf + i, 0u, __ATOMIC_RELAXED, __HIP_MEMORY_SCOPE_AGENT);
    return;
  }
  i -= 65536;
  if (i < 64) {
    __hip_atomic_store(bar + i, 0u, __ATOMIC_RELAXED, __HIP_MEMORY_SCOPE_AGENT);
    return;
  }
  i -= 64;
  if (i < 30720) { // feat1p pad rows 0 and 1001
    int b = i / 240; int r = i - b * 240;
    int row = (r < 120) ? 0 : 1001; int c = r % 120;
    feat1p[b * 120240 + row * 120 + c] = (bf16_t)0.f; return;
  }
  i -= 30720;
  if (i < 256) { feat1p[128 * 120240 + i] = (bf16_t)0.f; return; } // tail guard
  i -= 256;
  if (i < 65536) { cd[i] = 0.f; return; }
  i -= 65536;
  if (i < 131072) { int k = i & 1023; dec_in[i] = (k < 512) ? (bf16_t)c0[k] : (bf16_t)0.f; return; }
  i -= 131072;
  if (i < 120) {
    const float* cbs[6] = {cb0, cb1, cb2, cb3, cb4, cb5};
    cbias[i] = cbs[i / 20][i % 20]; return;
  }
}

// ---------------------------------------------------------------------------
// weight prep
// ---------------------------------------------------------------------------
// LSTM: Wl[dir][n'][384], n' = tile*64 + g*16 + u  <-  orig row g*256 + tile*16 + u
__global__ void k_prep_lstm(const float* wif, const float* whf, const float* bif, const float* bhf,
                            const float* wir, const float* whr, const float* bir, const float* bhr,
                            bf16_t* Wl, float* bl) {
  int row = blockIdx.x;            // 0..2047
  int dir = row >> 10; int np = row & 1023;
  int tile = np >> 6; int rem = np & 63; int g = rem >> 4; int u = rem & 15;
  int orow = g * 256 + tile * 16 + u;
  const float* wi = dir ? wir : wif;
  const float* wh = dir ? whr : whf;
  for (int k = threadIdx.x; k < 384; k += blockDim.x) {
    float v = (k < 128) ? wi[orow * 128 + k] : wh[orow * 256 + (k - 128)];
    Wl[row * 384 + k] = (bf16_t)v;
  }
  if (threadIdx.x == 0) {
    const float* bi = dir ? bir : bif;
    const float* bh = dir ? bhr : bhf;
    bl[row] = bi[orow] + bh[orow];
  }
}

// decoder: Wdec[n'][1024], n' = tile*64+g*16+u <- orig g*512+tile*16+u.
// k<512: Wi[:, :512]; k>=512: Wi[:,512+k'] + Wh[:,k']  (both multiply hd)
__global__ void k_prep_dec(const float* dwi, const float* dwh, const float* dbi, const float* dbh,
                           bf16_t* Wdec, float* bdec) {
  int np = blockIdx.x; // 0..2047
  int tile = np >> 6; int rem = np & 63; int g = rem >> 4; int u = rem & 15;
  int orow = g * 512 + tile * 16 + u;
  for (int k = threadIdx.x; k < 1024; k += blockDim.x) {
    float v;
    if (k < 512) v = dwi[orow * 1024 + k];
    else v = dwi[orow * 1024 + 512 + (k - 512)] + dwh[orow * 512 + (k - 512)];
    Wdec[np * 1024 + k] = (bf16_t)v;
  }
  if (threadIdx.x == 0) bdec[np] = dbi[orow] + dbh[orow];
}

// conv1 (im2col kk=k*32+c, rows padded to 32), conv2 (kk=k*120+ci, K padded 384), we, wd
__global__ void k_prep_misc(const float* cw0, const float* cw1, const float* cw2,
                            const float* cw3, const float* cw4, const float* cw5,
                            const float* conv2_w, const float* we_w, const float* wd_w,
                            bf16_t* Wc1, bf16_t* Wc2, bf16_t* Wwe, bf16_t* Wwd) {
  int i = blockIdx.x * 256 + threadIdx.x;
  if (i < 55296) {
    const float* cws[6] = {cw0, cw1, cw2, cw3, cw4, cw5};
    int br = 0;
    while (br < 5 && i >= WOFF[br + 1]) ++br;
    int K = KBS[br];
    int jj = i - WOFF[br];
    int kw = K * 32;
    int f = jj / kw; int rem = jj - f * kw; int k = rem >> 5; int c = rem & 31;
    float v = (f < 20) ? cws[br][(f * 32 + c) * K + k] : 0.f;
    Wc1[i] = (bf16_t)v;
    return;
  }
  i -= 55296;
  if (i < 49152) {
    int co = i / 384; int kk = i - co * 384;
    float v = 0.f;
    if (kk < 360) { int ci = kk % 120; int k = kk / 120; v = conv2_w[co * 360 + ci * 3 + k]; }
    Wc2[i] = (bf16_t)v;
    return;
  }
  i -= 49152;
  if (i < 131072) { Wwe[i] = (bf16_t)we_w[i]; return; }
  i -= 131072;
  if (i < 131072) { Wwd[i] = (bf16_t)wd_w[i]; return; }
}

// ---------------------------------------------------------------------------
// embedding -> embp [B][1020][32] bf16 (10 pad rows each side, zeros)
// ---------------------------------------------------------------------------
__global__ void k_embed(const int* x, const float* ew, bf16_t* embp) {
  int idx = blockIdx.x * 256 + threadIdx.x;
  if (idx >= 128 * 1020 * 32) return;
  int c = idx & 31; int rest = idx >> 5;
  int j = rest % 1020; int b = rest / 1020;
  float v = 0.f;
  int l = j - 10;
  if (l >= 0 && l < 1000) { int tok = x[b * 1000 + l]; v = ew[tok * 32 + c]; }
  embp[idx] = (bf16_t)v;
}

// ---------------------------------------------------------------------------
// conv1: per (M-tile of 128 rows, branch). MFMA GEMM, A rows contiguous windows.
// out: feat1p[b][l+1][branch*20+f], relu
// ---------------------------------------------------------------------------
__global__ void __launch_bounds__(256) k_conv1(const bf16_t* __restrict__ embp,
                                               const bf16_t* __restrict__ Wc1,
                                               const float* __restrict__ cbias,
                                               bf16_t* __restrict__ feat1p) {
  int tile = blockIdx.x, br = blockIdx.y;
  int Kb = KBS[br]; int p = Kb >> 1;
  const bf16_t* Wb = Wc1 + WOFF[br];
  int tid = threadIdx.x; int w = tid >> 6; int lane = tid & 63; int u = lane & 15; int q = lane >> 4;
  const bf16_t* arow[2];
#pragma unroll
  for (int mf = 0; mf < 2; ++mf) {
    int r = tile * 128 + w * 32 + mf * 16 + u;
    int b = r / 1000, l = r - b * 1000;
    arow[mf] = embp + b * 32640 + (l + 10 - p) * 32;
  }
  f32x4 acc[2][2];
#pragma unroll
  for (int mf = 0; mf < 2; ++mf)
#pragma unroll
    for (int nf = 0; nf < 2; ++nf) acc[mf][nf] = (f32x4){0.f, 0.f, 0.f, 0.f};
  int kw = Kb * 32;
  for (int kc = 0; kc < Kb; ++kc) {
    int kk = kc * 32 + q * 8;
    bf16x8 a0 = *(const bf16x8*)(arow[0] + kk);
    bf16x8 a1 = *(const bf16x8*)(arow[1] + kk);
    bf16x8 b0 = *(const bf16x8*)(Wb + u * kw + kk);
    bf16x8 b1 = *(const bf16x8*)(Wb + (16 + u) * kw + kk);
    acc[0][0] = mfma16(a0, b0, acc[0][0]);
    acc[0][1] = mfma16(a0, b1, acc[0][1]);
    acc[1][0] = mfma16(a1, b0, acc[1][0]);
    acc[1][1] = mfma16(a1, b1, acc[1][1]);
  }
#pragma unroll
  for (int nf = 0; nf < 2; ++nf) {
    int n = nf * 16 + u;
    if (n >= 20) continue;
    int fg = br * 20 + n;
    float bias = cbias[fg];
#pragma unroll
    for (int mf = 0; mf < 2; ++mf)
#pragma unroll
      for (int reg = 0; reg < 4; ++reg) {
        int r = tile * 128 + w * 32 + mf * 16 + q * 4 + reg;
        int b = r / 1000, l = r - b * 1000;
        float v = acc[mf][nf][reg] + bias;
        v = fmaxf(v, 0.f);
        feat1p[b * 120240 + (l + 1) * 120 + fg] = (bf16_t)v;
      }
  }
}

// ---------------------------------------------------------------------------
// conv2: MFMA GEMM M=128/block, N=128, K=384(pad of 360). out -> seq[L][B][128], relu
// ---------------------------------------------------------------------------
__global__ void __launch_bounds__(256) k_conv2(const bf16_t* __restrict__ feat1p,
                                               const bf16_t* __restrict__ Wc2,
                                               const float* __restrict__ c2b,
                                               bf16_t* __restrict__ seq) {
  int tile = blockIdx.x;
  int tid = threadIdx.x; int w = tid >> 6; int lane = tid & 63; int u = lane & 15; int q = lane >> 4;
  const bf16_t* arow[2];
#pragma unroll
  for (int mf = 0; mf < 2; ++mf) {
    int r = tile * 128 + w * 32 + mf * 16 + u;
    int b = r / 1000, l = r - b * 1000;
    arow[mf] = feat1p + b * 120240 + l * 120;   // covers real rows l-1..l+1 (+pad tail)
  }
  f32x4 acc[2][8];
#pragma unroll
  for (int mf = 0; mf < 2; ++mf)
#pragma unroll
    for (int nf = 0; nf < 8; ++nf) acc[mf][nf] = (f32x4){0.f, 0.f, 0.f, 0.f};
#pragma unroll
  for (int kc = 0; kc < 12; ++kc) {
    int kk = kc * 32 + q * 8;
    bf16x8 a0 = *(const bf16x8*)(arow[0] + kk);
    bf16x8 a1 = *(const bf16x8*)(arow[1] + kk);
#pragma unroll
    for (int nf = 0; nf < 8; ++nf) {
      bf16x8 bfr = *(const bf16x8*)(Wc2 + (nf * 16 + u) * 384 + kk);
      acc[0][nf] = mfma16(a0, bfr, acc[0][nf]);
      acc[1][nf] = mfma16(a1, bfr, acc[1][nf]);
    }
  }
#pragma unroll
  for (int nf = 0; nf < 8; ++nf) {
    int n = nf * 16 + u;
    float bias = c2b[n];
#pragma unroll
    for (int mf = 0; mf < 2; ++mf)
#pragma unroll
      for (int reg = 0; reg < 4; ++reg) {
        int r = tile * 128 + w * 32 + mf * 16 + q * 4 + reg;
        int b = r / 1000, l = r - b * 1000;
        float v = fmaxf(acc[mf][nf][reg] + bias, 0.f);
        seq[(l * 128 + b) * 128 + n] = (bf16_t)v;
      }
  }
}

// ---------------------------------------------------------------------------
// persistent BiLSTM: 32 WGs (16 N-tiles x 2 dirs), per-step spin barrier.
// h + barrier go through the Infinity Cache (relaxed agent atomics, sc0/sc1)
// -> no L2 invalidates, seq stays L2-resident. c stays in registers.
// ---------------------------------------------------------------------------
__global__ void __launch_bounds__(256) k_lstm(const bf16_t* __restrict__ seq,
                                              const bf16_t* __restrict__ Wl,
                                              const float* __restrict__ bl,
                                              bf16_t* hbuf, bf16_t* lstm_out, unsigned* bar) {
  const int bid = blockIdx.x;
  const int dir = bid >> 4;
  const int tile = bid & 15;
  const int tid = threadIdx.x;
  const int w = tid >> 6, lane = tid & 63, u = lane & 15, q = lane >> 4;

  __shared__ __align__(16) bf16_t Wlds[64 * 392];
  const bf16_t* Wg = Wl + (size_t)(dir * 1024 + tile * 64) * 384;
  for (int i = tid; i < 64 * 48; i += 256) {
    int rr = i / 48, cc = (i - rr * 48) * 8;
    *(bf16x8*)&Wlds[rr * 392 + cc] = *(const bf16x8*)&Wg[rr * 384 + cc];
  }
  float bias[4];
#pragma unroll
  for (int g = 0; g < 4; ++g) bias[g] = bl[dir * 1024 + tile * 64 + g * 16 + u];
  __syncthreads();

  const int j = tile * 16 + u;
  const int mA0 = w * 32 + u, mA1 = w * 32 + 16 + u;
  float creg[2][4] = {{0.f, 0.f, 0.f, 0.f}, {0.f, 0.f, 0.f, 0.f}};
  unsigned* cnt = bar + dir * 32;
  bf16_t* hb0 = hbuf + dir * (128 * 256);
  bf16_t* hb1 = hbuf + (2 + dir) * (128 * 256);

  for (int s = 0; s < 1000; ++s) {
    int t = dir ? (999 - s) : s;
    const bf16_t* hread = (s & 1) ? hb1 : hb0;
    bf16_t* hwrite = (s & 1) ? hb0 : hb1;

    f32x4 acc[2][4];
#pragma unroll
    for (int mf = 0; mf < 2; ++mf)
#pragma unroll
      for (int g = 0; g < 4; ++g) acc[mf][g] = (f32x4){0.f, 0.f, 0.f, 0.f};

    const bf16_t* seqt = seq + (size_t)t * 128 * 128;
#pragma unroll
    for (int kc = 0; kc < 12; ++kc) {
      int kk = kc * 32 + q * 8;
      bf16x8 a0, a1;
      if (kc < 4) {
        a0 = *(const bf16x8*)&seqt[mA0 * 128 + kk];
        a1 = *(const bf16x8*)&seqt[mA1 * 128 + kk];
      } else {
        a0 = load_h_ic8(&hread[mA0 * 256 + kk - 128]);
        a1 = load_h_ic8(&hread[mA1 * 256 + kk - 128]);
      }
#pragma unroll
      for (int g = 0; g < 4; ++g) {
        bf16x8 bfr = *(const bf16x8*)&Wlds[(g * 16 + u) * 392 + kk];
        acc[0][g] = mfma16(a0, bfr, acc[0][g]);
        acc[1][g] = mfma16(a1, bfr, acc[1][g]);
      }
    }
#pragma unroll
    for (int mf = 0; mf < 2; ++mf) {
#pragma unroll
      for (int reg = 0; reg < 4; ++reg) {
        int m = w * 32 + mf * 16 + q * 4 + reg;
        float gi = sigm(acc[mf][0][reg] + bias[0]);
        float gf = sigm(acc[mf][1][reg] + bias[1]);
        float gg = tanh_fast(acc[mf][2][reg] + bias[2]);
        float go = sigm(acc[mf][3][reg] + bias[3]);
        float c = gf * creg[mf][reg] + gi * gg;
        creg[mf][reg] = c;
        float h = go * tanh_fast(c);
        bf16_t hv = (bf16_t)h;
        store_h_ic(&hwrite[m * 256 + j], hv);             // IC-coherent
        lstm_out[((size_t)m * 1000 + t) * 512 + dir * 256 + j] = hv;  // cached, read next kernel
      }
    }
    if (s < 999) {
      __syncthreads();  // drains all lanes' stores (vmcnt 0) before arrival
      if (tid == 0) {
        __hip_atomic_fetch_add(cnt, 1u, __ATOMIC_RELAXED, __HIP_MEMORY_SCOPE_AGENT);
        unsigned target = 16u * (unsigned)(s + 1);
        int spins = 0;
        while (__hip_atomic_load(cnt, __ATOMIC_RELAXED, __HIP_MEMORY_SCOPE_AGENT) < target &&
               spins < (1 << 16)) {
          __builtin_amdgcn_s_sleep(1);
          ++spins;
        }
      }
      __syncthreads();
    }
  }
}

// ---------------------------------------------------------------------------
// e_enc = lstm_out @ we^T + we_b  (M=128000, N=256, K=512) -> bf16 [256][B*L]
// (n-major layout so k_score reads consecutive l per lane)
// ---------------------------------------------------------------------------
__global__ void __launch_bounds__(256) k_eenc(const bf16_t* __restrict__ lstm_out,
                                              const bf16_t* __restrict__ Wwe,
                                              const float* __restrict__ we_b,
                                              bf16_t* __restrict__ e_enc) {
  int mt = blockIdx.x; int n0 = blockIdx.y * 64;
  int tid = threadIdx.x; int w = tid >> 6; int lane = tid & 63; int u = lane & 15; int q = lane >> 4;
  const bf16_t* arow[2];
#pragma unroll
  for (int mf = 0; mf < 2; ++mf) {
    int r = mt * 128 + w * 32 + mf * 16 + u;
    arow[mf] = lstm_out + (size_t)r * 512;
  }
  f32x4 acc[2][4];
#pragma unroll
  for (int mf = 0; mf < 2; ++mf)
#pragma unroll
    for (int nf = 0; nf < 4; ++nf) acc[mf][nf] = (f32x4){0.f, 0.f, 0.f, 0.f};
#pragma unroll
  for (int kc = 0; kc < 16; ++kc) {
    int kk = kc * 32 + q * 8;
    bf16x8 a0 = *(const bf16x8*)(arow[0] + kk);
    bf16x8 a1 = *(const bf16x8*)(arow[1] + kk);
#pragma unroll
    for (int nf = 0; nf < 4; ++nf) {
      bf16x8 bfr = *(const bf16x8*)(Wwe + (n0 + nf * 16 + u) * 512 + kk);
      acc[0][nf] = mfma16(a0, bfr, acc[0][nf]);
      acc[1][nf] = mfma16(a1, bfr, acc[1][nf]);
    }
  }
#pragma unroll
  for (int nf = 0; nf < 4; ++nf) {
    int n = n0 + nf * 16 + u;
    float bias = we_b[n];
#pragma unroll
    for (int mf = 0; mf < 2; ++mf)
#pragma unroll
      for (int reg = 0; reg < 4; ++reg) {
        int r = mt * 128 + w * 32 + mf * 16 + q * 4 + reg;
        e_enc[(size_t)n * 128000 + r] = (bf16_t)(acc[mf][nf][reg] + bias);
      }
  }
}

// ---------------------------------------------------------------------------
// decoder gates: [128,2048] = dec_in[128,1024] @ Wdec^T, LSTMCell update
// ---------------------------------------------------------------------------
__global__ void __launch_bounds__(256) k_dec_gates(const bf16_t* __restrict__ dec_in,
                                                   const bf16_t* __restrict__ Wdec,
                                                   const float* __restrict__ bdec,
                                                   float* __restrict__ cd,
                                                   bf16_t* __restrict__ hd_new) {
  int tile = blockIdx.x;  // 0..31
  int tid = threadIdx.x; int w = tid >> 6; int lane = tid & 63; int u = lane & 15; int q = lane >> 4;
  int j = tile * 16 + u;
  float bias[4];
#pragma unroll
  for (int g = 0; g < 4; ++g) bias[g] = bdec[tile * 64 + g * 16 + u];
  int mA0 = w * 32 + u, mA1 = w * 32 + 16 + u;
  f32x4 acc[2][4];
#pragma unroll
  for (int mf = 0; mf < 2; ++mf)
#pragma unroll
    for (int g = 0; g < 4; ++g) acc[mf][g] = (f32x4){0.f, 0.f, 0.f, 0.f};
#pragma unroll 4
  for (int kc = 0; kc < 32; ++kc) {
    int kk = kc * 32 + q * 8;
    bf16x8 a0 = *(const bf16x8*)&dec_in[mA0 * 1024 + kk];
    bf16x8 a1 = *(const bf16x8*)&dec_in[mA1 * 1024 + kk];
#pragma unroll
    for (int g = 0; g < 4; ++g) {
      bf16x8 bfr = *(const bf16x8*)&Wdec[(size_t)(tile * 64 + g * 16 + u) * 1024 + kk];
      acc[0][g] = mfma16(a0, bfr, acc[0][g]);
      acc[1][g] = mfma16(a1, bfr, acc[1][g]);
    }
  }
#pragma unroll
  for (int mf = 0; mf < 2; ++mf) {
#pragma unroll
    for (int reg = 0; reg < 4; ++reg) {
      int m = w * 32 + mf * 16 + q * 4 + reg;
      float gi = sigm(acc[mf][0][reg] + bias[0]);
      float gf = sigm(acc[mf][1][reg] + bias[1]);
      float gg = tanh_fast(acc[mf][2][reg] + bias[2]);
      float go = sigm(acc[mf][3][reg] + bias[3]);
      float c = gf * cd[m * 512 + j] + gi * gg;
      cd[m * 512 + j] = c;
      hd_new[m * 512 + j] = (bf16_t)(go * tanh_fast(c));
    }
  }
}

// d = hd @ wd^T + wd_b   (M=128, N=256, K=512) -> fp32
__global__ void __launch_bounds__(256) k_d(const bf16_t* __restrict__ hd_new,
                                           const bf16_t* __restrict__ Wwd,
                                           const float* __restrict__ wd_b,
                                           float* __restrict__ dbuf) {
  int n0 = blockIdx.x * 64;
  int tid = threadIdx.x; int w = tid >> 6; int lane = tid & 63; int u = lane & 15; int q = lane >> 4;
  int mA0 = w * 32 + u, mA1 = w * 32 + 16 + u;
  f32x4 acc[2][4];
#pragma unroll
  for (int mf = 0; mf < 2; ++mf)
#pragma unroll
    for (int nf = 0; nf < 4; ++nf) acc[mf][nf] = (f32x4){0.f, 0.f, 0.f, 0.f};
#pragma unroll
  for (int kc = 0; kc < 16; ++kc) {
    int kk = kc * 32 + q * 8;
    bf16x8 a0 = *(const bf16x8*)&hd_new[mA0 * 512 + kk];
    bf16x8 a1 = *(const bf16x8*)&hd_new[mA1 * 512 + kk];
#pragma unroll
    for (int nf = 0; nf < 4; ++nf) {
      bf16x8 bfr = *(const bf16x8*)&Wwd[(n0 + nf * 16 + u) * 512 + kk];
      acc[0][nf] = mfma16(a0, bfr, acc[0][nf]);
      acc[1][nf] = mfma16(a1, bfr, acc[1][nf]);
    }
  }
#pragma unroll
  for (int nf = 0; nf < 4; ++nf) {
    int n = n0 + nf * 16 + u;
    float bias = wd_b[n];
#pragma unroll
    for (int mf = 0; mf < 2; ++mf)
#pragma unroll
      for (int reg = 0; reg < 4; ++reg) {
        int m = w * 32 + mf * 16 + q * 4 + reg;
        dbuf[m * 256 + n] = acc[mf][nf][reg] + bias;
      }
  }
}

// scores[b][l] = sum_n tanh(e_enc[n][b*1000+l] + d[n]) * v[n]; lanes = consecutive l
__global__ void __launch_bounds__(256) k_score(const bf16_t* __restrict__ e_enc,
                                               const float* __restrict__ dbuf,
                                               const float* __restrict__ attn_v,
                                               float* __restrict__ scores) {
  int b = blockIdx.y;
  int tid = threadIdx.x;
  __shared__ float dl[256], vl[256];
  dl[tid] = dbuf[b * 256 + tid];
  vl[tid] = attn_v[tid];
  __syncthreads();
  int l = blockIdx.x * 256 + tid;
  if (l >= 1000) return;
  const bf16_t* ep = e_enc + (size_t)b * 1000 + l;
  float acc = 0.f;
#pragma unroll 8
  for (int n = 0; n < 256; ++n)
    acc += tanh_fast((float)ep[(size_t)n * 128000] + dl[n]) * vl[n];
  scores[b * 1000 + l] = acc;
}

// softmax over L + ctx = sum_l w*lstm_out; writes dec_in = [ctx | hd_new]
// 512 threads: thread-per-h, l-outer -> coalesced lstm_out reads
__global__ void __launch_bounds__(512) k_softmax_ctx(const float* __restrict__ scores,
                                                     const bf16_t* __restrict__ lstm_out,
                                                     const bf16_t* __restrict__ hd_new,
                                                     bf16_t* __restrict__ dec_in) {
  int b = blockIdx.x;
  int tid = threadIdx.x; int wid = tid >> 6; int lane = tid & 63;
  __shared__ float wls[1000];
  __shared__ float red[8];
  __shared__ float sh_scalar;
  float mx = -1e30f;
  for (int l = tid; l < 1000; l += 512) {
    float s = scores[b * 1000 + l];
    wls[l] = s;
    mx = fmaxf(mx, s);
  }
#pragma unroll
  for (int off = 32; off > 0; off >>= 1) mx = fmaxf(mx, __shfl_xor(mx, off));
  if (lane == 0) red[wid] = mx;
  __syncthreads();
  if (tid == 0) {
    float m2 = red[0];
#pragma unroll
    for (int i = 1; i < 8; ++i) m2 = fmaxf(m2, red[i]);
    sh_scalar = m2;
  }
  __syncthreads();
  mx = sh_scalar;
  float sum = 0.f;
  for (int l = tid; l < 1000; l += 512) {
    float p = __expf(wls[l] - mx);
    wls[l] = p;
    sum += p;
  }
#pragma unroll
  for (int off = 32; off > 0; off >>= 1) sum += __shfl_xor(sum, off);
  if (lane == 0) red[wid] = sum;
  __syncthreads();
  if (tid == 0) {
    float s2 = red[0];
#pragma unroll
    for (int i = 1; i < 8; ++i) s2 += red[i];
    sh_scalar = s2;
  }
  __syncthreads();
  float inv = 1.f / sh_scalar;
  // ctx: thread tid owns h=tid; per l the block reads a full contiguous 1KB row
  float acc = 0.f;
  const bf16_t* lp = lstm_out + (size_t)b * 512000 + tid;
#pragma unroll 4
  for (int l = 0; l < 1000; ++l) acc += wls[l] * (float)lp[(size_t)l * 512];
  dec_in[b * 1024 + tid] = (bf16_t)(acc * inv);
  dec_in[b * 1024 + 512 + tid] = hd_new[b * 512 + tid];
}

// fc relu + out sigmoid
__global__ void __launch_bounds__(256) k_fc_out(const bf16_t* __restrict__ dec_in,
                                                const float* __restrict__ fc_w,
                                                const float* __restrict__ fc_b,
                                                const float* __restrict__ out_w,
                                                const float* __restrict__ out_b,
                                                float* __restrict__ out) {
  int b = blockIdx.x;
  int tid = threadIdx.x;
  __shared__ float ctxs[512], zs[512], parts[32][8];
  for (int jj = tid; jj < 512; jj += 256) ctxs[jj] = (float)dec_in[b * 1024 + jj];
  __syncthreads();
  for (int n = tid; n < 512; n += 256) {
    float acc = fc_b[n];
    const float* wr = fc_w + n * 512;
    for (int k = 0; k < 512; ++k) acc += ctxs[k] * wr[k];
    zs[n] = fmaxf(acc, 0.f);
  }
  __syncthreads();
  int col = tid & 7, part = tid >> 3;
  float acc = 0.f;
  const float* wo = out_w + col * 512;
  for (int k = part * 16; k < part * 16 + 16; ++k) acc += zs[k] * wo[k];
  parts[part][col] = acc;
  __syncthreads();
  if (tid < 8) {
    float a = out_b[tid];
    for (int p2 = 0; p2 < 32; ++p2) a += parts[p2][tid];
    out[b * 8 + tid] = 1.f / (1.f + __expf(-a));
  }
}

// ---------------------------------------------------------------------------
extern "C" void kernel_launch(void* const* d_in, const int* in_sizes, int n_in,
                              void* d_out, int out_size, void* d_ws, size_t ws_size,
                              hipStream_t stream) {
  const int*   x       = (const int*)d_in[0];
  const float* embed_w = (const float*)d_in[1];
  const float* cw[6]   = {(const float*)d_in[2], (const float*)d_in[4], (const float*)d_in[6],
                          (const float*)d_in[8], (const float*)d_in[10], (const float*)d_in[12]};
  const float* cb[6]   = {(const float*)d_in[3], (const float*)d_in[5], (const float*)d_in[7],
                          (const float*)d_in[9], (const float*)d_in[11], (const float*)d_in[13]};
  const float* conv2_w = (const float*)d_in[14];
  const float* conv2_b = (const float*)d_in[15];
  const float* lstm_wif = (const float*)d_in[16];
  const float* lstm_whf = (const float*)d_in[17];
  const float* lstm_bif = (const float*)d_in[18];
  const float* lstm_bhf = (const float*)d_in[19];
  const float* lstm_wir = (const float*)d_in[20];
  const float* lstm_whr = (const float*)d_in[21];
  const float* lstm_bir = (const float*)d_in[22];
  const float* lstm_bhr = (const float*)d_in[23];
  const float* dec_wi  = (const float*)d_in[24];
  const float* dec_wh  = (const float*)d_in[25];
  const float* dec_bi  = (const float*)d_in[26];
  const float* dec_bh  = (const float*)d_in[27];
  const float* attn_v  = (const float*)d_in[28];
  const float* we_w    = (const float*)d_in[29];
  const float* we_b    = (const float*)d_in[30];
  const float* wd_w    = (const float*)d_in[31];
  const float* wd_b    = (const float*)d_in[32];
  const float* fc_w    = (const float*)d_in[33];
  const float* fc_b    = (const float*)d_in[34];
  const float* out_w   = (const float*)d_in[35];
  const float* out_b   = (const float*)d_in[36];
  const float* c0      = (const float*)d_in[37];
  float* out = (float*)d_out;

  // ---- workspace layout with lifetime overlays ----
  // Region R (71,905,792 B): [feat1p 30.78M][seq 32.77M][embp 8.36M]
  //   all dead before k_eenc -> e_enc (65.54M) overlays R at offset 0.
  char* base = (char*)d_ws;
  bf16_t* feat1p  = (bf16_t*)(base + 0);                 // 30,781,952 B
  bf16_t* seq     = (bf16_t*)(base + 30781952);          // 32,768,000 B
  bf16_t* embp    = (bf16_t*)(base + 63549952);          //  8,355,840 B
  bf16_t* e_enc   = (bf16_t*)(base + 0);                 // 65,536,000 B (overlay)
  char* p = base + 71905792;                             // end of region R
  auto alloc = [&](size_t bytes) { char* r = p; p += (bytes + 255) & ~(size_t)255; return r; };
  bf16_t* lstm_out= (bf16_t*)alloc((size_t)128 * 1000 * 512 * 2);
  bf16_t* Wl      = (bf16_t*)alloc((size_t)2 * 1024 * 384 * 2);
  float*  bl      = (float*)alloc(2048 * 4);
  bf16_t* Wc1     = (bf16_t*)alloc(55296 * 2);
  float*  cbias   = (float*)alloc(512);
  bf16_t* Wc2     = (bf16_t*)alloc(49152 * 2);
  bf16_t* Wdec    = (bf16_t*)alloc((size_t)2048 * 1024 * 2);
  float*  bdec    = (float*)alloc(2048 * 4);
  bf16_t* Wwe     = (bf16_t*)alloc(131072 * 2);
  bf16_t* Wwd     = (bf16_t*)alloc(131072 * 2);
  bf16_t* hbuf    = (bf16_t*)alloc(131072 * 2);
  unsigned* bar   = (unsigned*)alloc(256);
  bf16_t* dec_in  = (bf16_t*)alloc(131072 * 2);
  bf16_t* hd_new  = (bf16_t*)alloc(65536 * 2);
  float*  cd      = (float*)alloc(65536 * 4);
  float*  dbuf    = (float*)alloc(32768 * 4);
  float*  scores  = (float*)alloc(128000 * 4);
  (void)ws_size; (void)n_in; (void)in_sizes; (void)out_size;

  k_init<<<1146, 256, 0, stream>>>(hbuf, bar, feat1p, cd, dec_in, cbias, c0,
                                   cb[0], cb[1], cb[2], cb[3], cb[4], cb[5]);
  k_prep_lstm<<<2048, 128, 0, stream>>>(lstm_wif, lstm_whf, lstm_bif, lstm_bhf,
                                        lstm_wir, lstm_whr, lstm_bir, lstm_bhr, Wl, bl);
  k_prep_dec<<<2048, 256, 0, stream>>>(dec_wi, dec_wh, dec_bi, dec_bh, Wdec, bdec);
  k_prep_misc<<<1432, 256, 0, stream>>>(cw[0], cw[1], cw[2], cw[3], cw[4], cw[5],
                                        conv2_w, we_w, wd_w, Wc1, Wc2, Wwe, Wwd);
  k_embed<<<16320, 256, 0, stream>>>(x, embed_w, embp);
  k_conv1<<<dim3(1000, 6), 256, 0, stream>>>(embp, Wc1, cbias, feat1p);
  k_conv2<<<1000, 256, 0, stream>>>(feat1p, Wc2, conv2_b, seq);
  k_lstm<<<32, 256, 0, stream>>>(seq, Wl, bl, hbuf, lstm_out, bar);
  k_eenc<<<dim3(1000, 4), 256, 0, stream>>>(lstm_out, Wwe, we_b, e_enc);
  for (int step = 0; step < 10; ++step) {
    k_dec_gates<<<32, 256, 0, stream>>>(dec_in, Wdec, bdec, cd, hd_new);
    k_d<<<4, 256, 0, stream>>>(hd_new, Wwd, wd_b, dbuf);
    k_score<<<dim3(4, 128), 256, 0, stream>>>(e_enc, dbuf, attn_v, scores);
    k_softmax_ctx<<<128, 512, 0, stream>>>(scores, lstm_out, hd_new, dec_in);
  }
  k_fc_out<<<128, 256, 0, stream>>>(dec_in, fc_w, fc_b, out_w, out_b, out);
}

// Round 4
// 7066.250 us; speedup vs baseline: 1.8163x; 1.8163x over previous
//
#include <hip/hip_runtime.h>
#include <hip/hip_bf16.h>
#include <math.h>

// ---------------------------------------------------------------------------
// DeepLoc model on MI355X.  B=128, L=1000, E=32, conv branches K={1,3,5,9,15,21}
// NF=20 -> 120ch, conv2 -> 128ch, BiLSTM H=256/dir, decoder LSTMCell H=512,
// attention over L, 10 decoder steps, fc 512 -> out 8 (sigmoid).
//
// R3 -> R4 (R3: 12.8 ms, k_lstm 10.9 ms; FETCH unchanged vs R2 => traffic is
// compulsory cross-XCD seq duplication, kernel is LATENCY-bound):
//  * h-history IS lstm_out: H[t+1][dir][b][256], each slab written once via
//    IC-atomics (sc0/sc1) -> consumers use plain WIDE cached loads (cold
//    lines can't be stale). Halves write traffic, kills scalar-atomic loads.
//  * flag-array barrier (1 relaxed store + 16-lane poll/ballot) instead of
//    16 serialized fetch_adds on one counter.
//  * seq[t+-1] prefetched into VGPRs before the barrier (HBM latency overlaps
//    barrier wait).
//  * decoder: d transposed to [n][b]; k_score fully coalesced; e_enc rows
//    indexed r = l*128+b.
// ---------------------------------------------------------------------------

typedef __bf16 bf16_t;
typedef __bf16 bf16x8 __attribute__((ext_vector_type(8)));
typedef float f32x4 __attribute__((ext_vector_type(4)));

__device__ __constant__ int KBS[6]  = {1, 3, 5, 9, 15, 21};
__device__ __constant__ int WOFF[6] = {0, 1024, 4096, 9216, 18432, 33792}; // elem offsets (1024*K cum)

__device__ inline f32x4 mfma16(bf16x8 a, bf16x8 b, f32x4 c) {
  return __builtin_amdgcn_mfma_f32_16x16x32_bf16(a, b, c, 0, 0, 0);
}
__device__ inline float sigm(float x) { return 1.f / (1.f + __expf(-x)); }
__device__ inline float tanh_fast(float x) {
  x = fminf(15.f, fmaxf(-15.f, x));
  float e = __expf(2.f * x);
  return (e - 1.f) / (e + 1.f);
}

// IC-coherent store (sc0/sc1): bypasses L1/L2, globally visible, no cache inv
__device__ inline void store_h_ic(bf16_t* p, bf16_t v) {
  unsigned short b = __builtin_bit_cast(unsigned short, v);
  __hip_atomic_store((unsigned short*)p, b, __ATOMIC_RELAXED, __HIP_MEMORY_SCOPE_AGENT);
}

// ---------------------------------------------------------------------------
// init: zero H boundary slabs (IC)/barriers/pads, dec_in = [c0|0], cbias concat
// ---------------------------------------------------------------------------
__global__ void k_init(bf16_t* H, unsigned* bar, bf16_t* feat1p, float* cd,
                       bf16_t* dec_in, float* cbias, const float* c0,
                       const float* cb0, const float* cb1, const float* cb2,
                       const float* cb3, const float* cb4, const float* cb5) {
  int i = blockIdx.x * 256 + threadIdx.x;
  if (i < 65536) {  // H slab 0 and slab 1001 zeros (32768 uints each), via IC
    unsigned* Hu = (unsigned*)H;
    size_t off = (i < 32768) ? (size_t)i : ((size_t)1001 * 32768 + (i - 32768));
    __hip_atomic_store(Hu + off, 0u, __ATOMIC_RELAXED, __HIP_MEMORY_SCOPE_AGENT);
    return;
  }
  i -= 65536;
  if (i < 512) {
    __hip_atomic_store(bar + i, 0u, __ATOMIC_RELAXED, __HIP_MEMORY_SCOPE_AGENT);
    return;
  }
  i -= 512;
  if (i < 30720) { // feat1p pad rows 0 and 1001
    int b = i / 240; int r = i - b * 240;
    int row = (r < 120) ? 0 : 1001; int c = r % 120;
    feat1p[b * 120240 + row * 120 + c] = (bf16_t)0.f; return;
  }
  i -= 30720;
  if (i < 256) { feat1p[128 * 120240 + i] = (bf16_t)0.f; return; } // tail guard
  i -= 256;
  if (i < 65536) { cd[i] = 0.f; return; }
  i -= 65536;
  if (i < 131072) { int k = i & 1023; dec_in[i] = (k < 512) ? (bf16_t)c0[k] : (bf16_t)0.f; return; }
  i -= 131072;
  if (i < 120) {
    const float* cbs[6] = {cb0, cb1, cb2, cb3, cb4, cb5};
    cbias[i] = cbs[i / 20][i % 20]; return;
  }
}

// ---------------------------------------------------------------------------
// weight prep
// ---------------------------------------------------------------------------
// LSTM: Wl[dir][n'][384], n' = tile*64 + g*16 + u  <-  orig row g*256 + tile*16 + u
__global__ void k_prep_lstm(const float* wif, const float* whf, const float* bif, const float* bhf,
                            const float* wir, const float* whr, const float* bir, const float* bhr,
                            bf16_t* Wl, float* bl) {
  int row = blockIdx.x;            // 0..2047
  int dir = row >> 10; int np = row & 1023;
  int tile = np >> 6; int rem = np & 63; int g = rem >> 4; int u = rem & 15;
  int orow = g * 256 + tile * 16 + u;
  const float* wi = dir ? wir : wif;
  const float* wh = dir ? whr : whf;
  for (int k = threadIdx.x; k < 384; k += blockDim.x) {
    float v = (k < 128) ? wi[orow * 128 + k] : wh[orow * 256 + (k - 128)];
    Wl[row * 384 + k] = (bf16_t)v;
  }
  if (threadIdx.x == 0) {
    const float* bi = dir ? bir : bif;
    const float* bh = dir ? bhr : bhf;
    bl[row] = bi[orow] + bh[orow];
  }
}

// decoder: Wdec[n'][1024], n' = tile*64+g*16+u <- orig g*512+tile*16+u.
__global__ void k_prep_dec(const float* dwi, const float* dwh, const float* dbi, const float* dbh,
                           bf16_t* Wdec, float* bdec) {
  int np = blockIdx.x; // 0..2047
  int tile = np >> 6; int rem = np & 63; int g = rem >> 4; int u = rem & 15;
  int orow = g * 512 + tile * 16 + u;
  for (int k = threadIdx.x; k < 1024; k += blockDim.x) {
    float v;
    if (k < 512) v = dwi[orow * 1024 + k];
    else v = dwi[orow * 1024 + 512 + (k - 512)] + dwh[orow * 512 + (k - 512)];
    Wdec[np * 1024 + k] = (bf16_t)v;
  }
  if (threadIdx.x == 0) bdec[np] = dbi[orow] + dbh[orow];
}

// conv1 (im2col kk=k*32+c, rows padded to 32), conv2 (kk=k*120+ci, K pad 384), we, wd
__global__ void k_prep_misc(const float* cw0, const float* cw1, const float* cw2,
                            const float* cw3, const float* cw4, const float* cw5,
                            const float* conv2_w, const float* we_w, const float* wd_w,
                            bf16_t* Wc1, bf16_t* Wc2, bf16_t* Wwe, bf16_t* Wwd) {
  int i = blockIdx.x * 256 + threadIdx.x;
  if (i < 55296) {
    const float* cws[6] = {cw0, cw1, cw2, cw3, cw4, cw5};
    int br = 0;
    while (br < 5 && i >= WOFF[br + 1]) ++br;
    int K = KBS[br];
    int jj = i - WOFF[br];
    int kw = K * 32;
    int f = jj / kw; int rem = jj - f * kw; int k = rem >> 5; int c = rem & 31;
    float v = (f < 20) ? cws[br][(f * 32 + c) * K + k] : 0.f;
    Wc1[i] = (bf16_t)v;
    return;
  }
  i -= 55296;
  if (i < 49152) {
    int co = i / 384; int kk = i - co * 384;
    float v = 0.f;
    if (kk < 360) { int ci = kk % 120; int k = kk / 120; v = conv2_w[co * 360 + ci * 3 + k]; }
    Wc2[i] = (bf16_t)v;
    return;
  }
  i -= 49152;
  if (i < 131072) { Wwe[i] = (bf16_t)we_w[i]; return; }
  i -= 131072;
  if (i < 131072) { Wwd[i] = (bf16_t)wd_w[i]; return; }
}

// ---------------------------------------------------------------------------
// embedding -> embp [B][1020][32] bf16 (10 pad rows each side, zeros)
// ---------------------------------------------------------------------------
__global__ void k_embed(const int* x, const float* ew, bf16_t* embp) {
  int idx = blockIdx.x * 256 + threadIdx.x;
  if (idx >= 128 * 1020 * 32) return;
  int c = idx & 31; int rest = idx >> 5;
  int j = rest % 1020; int b = rest / 1020;
  float v = 0.f;
  int l = j - 10;
  if (l >= 0 && l < 1000) { int tok = x[b * 1000 + l]; v = ew[tok * 32 + c]; }
  embp[idx] = (bf16_t)v;
}

// ---------------------------------------------------------------------------
// conv1: per (M-tile of 128 rows, branch). out: feat1p[b][l+1][branch*20+f], relu
// ---------------------------------------------------------------------------
__global__ void __launch_bounds__(256) k_conv1(const bf16_t* __restrict__ embp,
                                               const bf16_t* __restrict__ Wc1,
                                               const float* __restrict__ cbias,
                                               bf16_t* __restrict__ feat1p) {
  int tile = blockIdx.x, br = blockIdx.y;
  int Kb = KBS[br]; int p = Kb >> 1;
  const bf16_t* Wb = Wc1 + WOFF[br];
  int tid = threadIdx.x; int w = tid >> 6; int lane = tid & 63; int u = lane & 15; int q = lane >> 4;
  const bf16_t* arow[2];
#pragma unroll
  for (int mf = 0; mf < 2; ++mf) {
    int r = tile * 128 + w * 32 + mf * 16 + u;
    int b = r / 1000, l = r - b * 1000;
    arow[mf] = embp + b * 32640 + (l + 10 - p) * 32;
  }
  f32x4 acc[2][2];
#pragma unroll
  for (int mf = 0; mf < 2; ++mf)
#pragma unroll
    for (int nf = 0; nf < 2; ++nf) acc[mf][nf] = (f32x4){0.f, 0.f, 0.f, 0.f};
  int kw = Kb * 32;
  for (int kc = 0; kc < Kb; ++kc) {
    int kk = kc * 32 + q * 8;
    bf16x8 a0 = *(const bf16x8*)(arow[0] + kk);
    bf16x8 a1 = *(const bf16x8*)(arow[1] + kk);
    bf16x8 b0 = *(const bf16x8*)(Wb + u * kw + kk);
    bf16x8 b1 = *(const bf16x8*)(Wb + (16 + u) * kw + kk);
    acc[0][0] = mfma16(a0, b0, acc[0][0]);
    acc[0][1] = mfma16(a0, b1, acc[0][1]);
    acc[1][0] = mfma16(a1, b0, acc[1][0]);
    acc[1][1] = mfma16(a1, b1, acc[1][1]);
  }
#pragma unroll
  for (int nf = 0; nf < 2; ++nf) {
    int n = nf * 16 + u;
    if (n >= 20) continue;
    int fg = br * 20 + n;
    float bias = cbias[fg];
#pragma unroll
    for (int mf = 0; mf < 2; ++mf)
#pragma unroll
      for (int reg = 0; reg < 4; ++reg) {
        int r = tile * 128 + w * 32 + mf * 16 + q * 4 + reg;
        int b = r / 1000, l = r - b * 1000;
        float v = acc[mf][nf][reg] + bias;
        v = fmaxf(v, 0.f);
        feat1p[b * 120240 + (l + 1) * 120 + fg] = (bf16_t)v;
      }
  }
}

// ---------------------------------------------------------------------------
// conv2: GEMM M=128/block, N=128, K=384(pad of 360). out -> seq[L][B][128], relu
// ---------------------------------------------------------------------------
__global__ void __launch_bounds__(256) k_conv2(const bf16_t* __restrict__ feat1p,
                                               const bf16_t* __restrict__ Wc2,
                                               const float* __restrict__ c2b,
                                               bf16_t* __restrict__ seq) {
  int tile = blockIdx.x;
  int tid = threadIdx.x; int w = tid >> 6; int lane = tid & 63; int u = lane & 15; int q = lane >> 4;
  const bf16_t* arow[2];
#pragma unroll
  for (int mf = 0; mf < 2; ++mf) {
    int r = tile * 128 + w * 32 + mf * 16 + u;
    int b = r / 1000, l = r - b * 1000;
    arow[mf] = feat1p + b * 120240 + l * 120;
  }
  f32x4 acc[2][8];
#pragma unroll
  for (int mf = 0; mf < 2; ++mf)
#pragma unroll
    for (int nf = 0; nf < 8; ++nf) acc[mf][nf] = (f32x4){0.f, 0.f, 0.f, 0.f};
#pragma unroll
  for (int kc = 0; kc < 12; ++kc) {
    int kk = kc * 32 + q * 8;
    bf16x8 a0 = *(const bf16x8*)(arow[0] + kk);
    bf16x8 a1 = *(const bf16x8*)(arow[1] + kk);
#pragma unroll
    for (int nf = 0; nf < 8; ++nf) {
      bf16x8 bfr = *(const bf16x8*)(Wc2 + (nf * 16 + u) * 384 + kk);
      acc[0][nf] = mfma16(a0, bfr, acc[0][nf]);
      acc[1][nf] = mfma16(a1, bfr, acc[1][nf]);
    }
  }
#pragma unroll
  for (int nf = 0; nf < 8; ++nf) {
    int n = nf * 16 + u;
    float bias = c2b[n];
#pragma unroll
    for (int mf = 0; mf < 2; ++mf)
#pragma unroll
      for (int reg = 0; reg < 4; ++reg) {
        int r = tile * 128 + w * 32 + mf * 16 + q * 4 + reg;
        int b = r / 1000, l = r - b * 1000;
        float v = fmaxf(acc[mf][nf][reg] + bias, 0.f);
        seq[(l * 128 + b) * 128 + n] = (bf16_t)v;
      }
  }
}

// ---------------------------------------------------------------------------
// persistent BiLSTM: 32 WGs (16 N-tiles x 2 dirs).
// H[t+1][dir][b][256] is both h-history and lstm_out; producers IC-store,
// consumers plain wide loads (cold addresses). Flag-array barrier, seq
// prefetched into VGPRs before the barrier.
// ---------------------------------------------------------------------------
__global__ void __launch_bounds__(256) k_lstm(const bf16_t* __restrict__ seq,
                                              const bf16_t* __restrict__ Wl,
                                              const float* __restrict__ bl,
                                              bf16_t* H, unsigned* bar) {
  const int bid = blockIdx.x;
  const int dir = bid >> 4;
  const int tile = bid & 15;
  const int tid = threadIdx.x;
  const int w = tid >> 6, lane = tid & 63, u = lane & 15, q = lane >> 4;

  __shared__ __align__(16) bf16_t Wlds[64 * 392];
  const bf16_t* Wg = Wl + (size_t)(dir * 1024 + tile * 64) * 384;
  for (int i = tid; i < 64 * 48; i += 256) {
    int rr = i / 48, cc = (i - rr * 48) * 8;
    *(bf16x8*)&Wlds[rr * 392 + cc] = *(const bf16x8*)&Wg[rr * 384 + cc];
  }
  float bias[4];
#pragma unroll
  for (int g = 0; g < 4; ++g) bias[g] = bl[dir * 1024 + tile * 64 + g * 16 + u];
  __syncthreads();

  const int j = tile * 16 + u;
  const int mA0 = w * 32 + u, mA1 = w * 32 + 16 + u;
  float creg[2][4] = {{0.f, 0.f, 0.f, 0.f}, {0.f, 0.f, 0.f, 0.f}};
  unsigned* flg = bar + dir * 256;  // 16 flags, 64B apart

  // prime seq prefetch for s=0
  bf16x8 pf[2][4];
  {
    const bf16_t* seqt = seq + (size_t)(dir ? 999 : 0) * 16384;
#pragma unroll
    for (int kc = 0; kc < 4; ++kc) {
      pf[0][kc] = *(const bf16x8*)&seqt[mA0 * 128 + kc * 32 + q * 8];
      pf[1][kc] = *(const bf16x8*)&seqt[mA1 * 128 + kc * 32 + q * 8];
    }
  }

  for (int s = 0; s < 1000; ++s) {
    int t = dir ? (999 - s) : s;
    // input h slab: fwd -> slab t (h_{t-1}); rev -> slab t+2 (h_{t+1}); 0/1001 are zeros
    const bf16_t* hread = H + ((size_t)(dir ? (t + 2) : t) * 2 + dir) * 32768;
    bf16_t* hwrite = H + ((size_t)(t + 1) * 2 + dir) * 32768;

    // issue wide h loads early (plain cached; cold lines, IC-backed)
    bf16x8 hv0[8], hv1[8];
#pragma unroll
    for (int i = 0; i < 8; ++i) {
      hv0[i] = *(const bf16x8*)&hread[mA0 * 256 + i * 32 + q * 8];
      hv1[i] = *(const bf16x8*)&hread[mA1 * 256 + i * 32 + q * 8];
    }

    f32x4 acc[2][4];
#pragma unroll
    for (int mf = 0; mf < 2; ++mf)
#pragma unroll
      for (int g = 0; g < 4; ++g) acc[mf][g] = (f32x4){0.f, 0.f, 0.f, 0.f};

    // seq part (prefetched regs), k = 0..127
#pragma unroll
    for (int kc = 0; kc < 4; ++kc) {
      int kk = kc * 32 + q * 8;
#pragma unroll
      for (int g = 0; g < 4; ++g) {
        bf16x8 bfr = *(const bf16x8*)&Wlds[(g * 16 + u) * 392 + kk];
        acc[0][g] = mfma16(pf[0][kc], bfr, acc[0][g]);
        acc[1][g] = mfma16(pf[1][kc], bfr, acc[1][g]);
      }
    }
    // h part, k = 128..383
#pragma unroll
    for (int i = 0; i < 8; ++i) {
      int kk = 128 + i * 32 + q * 8;
#pragma unroll
      for (int g = 0; g < 4; ++g) {
        bf16x8 bfr = *(const bf16x8*)&Wlds[(g * 16 + u) * 392 + kk];
        acc[0][g] = mfma16(hv0[i], bfr, acc[0][g]);
        acc[1][g] = mfma16(hv1[i], bfr, acc[1][g]);
      }
    }

    // prefetch next step's seq tile (overlaps gate math + barrier wait)
    if (s < 999) {
      const bf16_t* seqn = seq + (size_t)(dir ? (t - 1) : (t + 1)) * 16384;
#pragma unroll
      for (int kc = 0; kc < 4; ++kc) {
        pf[0][kc] = *(const bf16x8*)&seqn[mA0 * 128 + kc * 32 + q * 8];
        pf[1][kc] = *(const bf16x8*)&seqn[mA1 * 128 + kc * 32 + q * 8];
      }
    }

#pragma unroll
    for (int mf = 0; mf < 2; ++mf) {
#pragma unroll
      for (int reg = 0; reg < 4; ++reg) {
        int m = w * 32 + mf * 16 + q * 4 + reg;
        float gi = sigm(acc[mf][0][reg] + bias[0]);
        float gf = sigm(acc[mf][1][reg] + bias[1]);
        float gg = tanh_fast(acc[mf][2][reg] + bias[2]);
        float go = sigm(acc[mf][3][reg] + bias[3]);
        float c = gf * creg[mf][reg] + gi * gg;
        creg[mf][reg] = c;
        store_h_ic(&hwrite[m * 256 + j], (bf16_t)(go * tanh_fast(c)));
      }
    }

    if (s < 999) {
      __syncthreads();  // vmcnt(0) drain: all h IC-stores complete & visible
      if (tid == 0)
        __hip_atomic_store(&flg[tile * 16], (unsigned)(s + 1), __ATOMIC_RELAXED,
                           __HIP_MEMORY_SCOPE_AGENT);
      if (w == 0) {
        unsigned target = (unsigned)(s + 1);
        int spins = 0;
        while (spins < (1 << 17)) {
          unsigned f = (lane < 16)
              ? __hip_atomic_load(&flg[lane * 16], __ATOMIC_RELAXED, __HIP_MEMORY_SCOPE_AGENT)
              : target;
          if (__ballot(f >= target) == ~0ull) break;
          __builtin_amdgcn_s_sleep(1);
          ++spins;
        }
      }
      __syncthreads();
    }
  }
}

// ---------------------------------------------------------------------------
// e_enc[n][l*128+b] = (H[l+1] @ we^T + we_b), M rows r = l*128+b, K=512
// ---------------------------------------------------------------------------
__global__ void __launch_bounds__(256) k_eenc(const bf16_t* __restrict__ H,
                                              const bf16_t* __restrict__ Wwe,
                                              const float* __restrict__ we_b,
                                              bf16_t* __restrict__ e_enc) {
  int mt = blockIdx.x;  // = l
  int n0 = blockIdx.y * 64;
  int tid = threadIdx.x; int w = tid >> 6; int lane = tid & 63; int u = lane & 15; int q = lane >> 4;
  const bf16_t* af[2]; const bf16_t* ar[2];
#pragma unroll
  for (int mf = 0; mf < 2; ++mf) {
    int b = w * 32 + mf * 16 + u;
    af[mf] = H + (((size_t)(mt + 1) * 2 + 0) * 128 + b) * 256;
    ar[mf] = H + (((size_t)(mt + 1) * 2 + 1) * 128 + b) * 256;
  }
  f32x4 acc[2][4];
#pragma unroll
  for (int mf = 0; mf < 2; ++mf)
#pragma unroll
    for (int nf = 0; nf < 4; ++nf) acc[mf][nf] = (f32x4){0.f, 0.f, 0.f, 0.f};
#pragma unroll
  for (int kc = 0; kc < 16; ++kc) {
    int kk = (kc & 7) * 32 + q * 8;
    bf16x8 a0 = (kc < 8) ? *(const bf16x8*)(af[0] + kk) : *(const bf16x8*)(ar[0] + kk);
    bf16x8 a1 = (kc < 8) ? *(const bf16x8*)(af[1] + kk) : *(const bf16x8*)(ar[1] + kk);
#pragma unroll
    for (int nf = 0; nf < 4; ++nf) {
      bf16x8 bfr = *(const bf16x8*)(Wwe + (n0 + nf * 16 + u) * 512 + kc * 32 + q * 8);
      acc[0][nf] = mfma16(a0, bfr, acc[0][nf]);
      acc[1][nf] = mfma16(a1, bfr, acc[1][nf]);
    }
  }
#pragma unroll
  for (int nf = 0; nf < 4; ++nf) {
    int n = n0 + nf * 16 + u;
    float bias = we_b[n];
#pragma unroll
    for (int mf = 0; mf < 2; ++mf)
#pragma unroll
      for (int reg = 0; reg < 4; ++reg) {
        int r = mt * 128 + w * 32 + mf * 16 + q * 4 + reg;
        e_enc[(size_t)n * 128000 + r] = (bf16_t)(acc[mf][nf][reg] + bias);
      }
  }
}

// ---------------------------------------------------------------------------
// decoder gates: [128,2048] = dec_in[128,1024] @ Wdec^T, LSTMCell update
// ---------------------------------------------------------------------------
__global__ void __launch_bounds__(256) k_dec_gates(const bf16_t* __restrict__ dec_in,
                                                   const bf16_t* __restrict__ Wdec,
                                                   const float* __restrict__ bdec,
                                                   float* __restrict__ cd,
                                                   bf16_t* __restrict__ hd_new) {
  int tile = blockIdx.x;  // 0..31
  int tid = threadIdx.x; int w = tid >> 6; int lane = tid & 63; int u = lane & 15; int q = lane >> 4;
  int j = tile * 16 + u;
  float bias[4];
#pragma unroll
  for (int g = 0; g < 4; ++g) bias[g] = bdec[tile * 64 + g * 16 + u];
  int mA0 = w * 32 + u, mA1 = w * 32 + 16 + u;
  f32x4 acc[2][4];
#pragma unroll
  for (int mf = 0; mf < 2; ++mf)
#pragma unroll
    for (int g = 0; g < 4; ++g) acc[mf][g] = (f32x4){0.f, 0.f, 0.f, 0.f};
#pragma unroll 4
  for (int kc = 0; kc < 32; ++kc) {
    int kk = kc * 32 + q * 8;
    bf16x8 a0 = *(const bf16x8*)&dec_in[mA0 * 1024 + kk];
    bf16x8 a1 = *(const bf16x8*)&dec_in[mA1 * 1024 + kk];
#pragma unroll
    for (int g = 0; g < 4; ++g) {
      bf16x8 bfr = *(const bf16x8*)&Wdec[(size_t)(tile * 64 + g * 16 + u) * 1024 + kk];
      acc[0][g] = mfma16(a0, bfr, acc[0][g]);
      acc[1][g] = mfma16(a1, bfr, acc[1][g]);
    }
  }
#pragma unroll
  for (int mf = 0; mf < 2; ++mf) {
#pragma unroll
    for (int reg = 0; reg < 4; ++reg) {
      int m = w * 32 + mf * 16 + q * 4 + reg;
      float gi = sigm(acc[mf][0][reg] + bias[0]);
      float gf = sigm(acc[mf][1][reg] + bias[1]);
      float gg = tanh_fast(acc[mf][2][reg] + bias[2]);
      float go = sigm(acc[mf][3][reg] + bias[3]);
      float c = gf * cd[m * 512 + j] + gi * gg;
      cd[m * 512 + j] = c;
      hd_new[m * 512 + j] = (bf16_t)(go * tanh_fast(c));
    }
  }
}

// d_t[n][b] = (hd @ wd^T + wd_b)^T   (M=128, N=256, K=512) -> fp32 transposed
__global__ void __launch_bounds__(256) k_d(const bf16_t* __restrict__ hd_new,
                                           const bf16_t* __restrict__ Wwd,
                                           const float* __restrict__ wd_b,
                                           float* __restrict__ d_t) {
  int n0 = blockIdx.x * 64;
  int tid = threadIdx.x; int w = tid >> 6; int lane = tid & 63; int u = lane & 15; int q = lane >> 4;
  int mA0 = w * 32 + u, mA1 = w * 32 + 16 + u;
  f32x4 acc[2][4];
#pragma unroll
  for (int mf = 0; mf < 2; ++mf)
#pragma unroll
    for (int nf = 0; nf < 4; ++nf) acc[mf][nf] = (f32x4){0.f, 0.f, 0.f, 0.f};
#pragma unroll
  for (int kc = 0; kc < 16; ++kc) {
    int kk = kc * 32 + q * 8;
    bf16x8 a0 = *(const bf16x8*)&hd_new[mA0 * 512 + kk];
    bf16x8 a1 = *(const bf16x8*)&hd_new[mA1 * 512 + kk];
#pragma unroll
    for (int nf = 0; nf < 4; ++nf) {
      bf16x8 bfr = *(const bf16x8*)&Wwd[(n0 + nf * 16 + u) * 512 + kk];
      acc[0][nf] = mfma16(a0, bfr, acc[0][nf]);
      acc[1][nf] = mfma16(a1, bfr, acc[1][nf]);
    }
  }
#pragma unroll
  for (int nf = 0; nf < 4; ++nf) {
    int n = n0 + nf * 16 + u;
    float bias = wd_b[n];
#pragma unroll
    for (int mf = 0; mf < 2; ++mf)
#pragma unroll
      for (int reg = 0; reg < 4; ++reg) {
        int m = w * 32 + mf * 16 + q * 4 + reg;
        d_t[n * 128 + m] = acc[mf][nf][reg] + bias;
      }
  }
}

// scores[b][l] = sum_n tanh(e_enc[n][l*128+b] + d_t[n][b]) * v[n]
// 256 thr = 2 l-rows x 128 b-lanes; both streams coalesced
__global__ void __launch_bounds__(256) k_score(const bf16_t* __restrict__ e_enc,
                                               const float* __restrict__ d_t,
                                               const float* __restrict__ attn_v,
                                               float* __restrict__ scores) {
  int tid = threadIdx.x;
  __shared__ float vl[256];
  vl[tid] = attn_v[tid];
  __syncthreads();
  int sub = tid >> 7, b = tid & 127;
  int l = blockIdx.x * 2 + sub;
  const bf16_t* ep = e_enc + (size_t)l * 128 + b;
  const float* dp = d_t + b;
  float acc = 0.f;
#pragma unroll 8
  for (int n = 0; n < 256; ++n)
    acc += tanh_fast((float)ep[(size_t)n * 128000] + dp[n * 128]) * vl[n];
  scores[b * 1000 + l] = acc;
}

// softmax over L + ctx = sum_l w * H; writes dec_in = [ctx | hd_new]
// 512 threads: tid = dir*256+hh; per-l block reads 2x contiguous 512B
__global__ void __launch_bounds__(512) k_softmax_ctx(const float* __restrict__ scores,
                                                     const bf16_t* __restrict__ H,
                                                     const bf16_t* __restrict__ hd_new,
                                                     bf16_t* __restrict__ dec_in) {
  int b = blockIdx.x;
  int tid = threadIdx.x; int wid = tid >> 6; int lane = tid & 63;
  __shared__ float wls[1000];
  __shared__ float red[8];
  __shared__ float sh_scalar;
  float mx = -1e30f;
  for (int l = tid; l < 1000; l += 512) {
    float s = scores[b * 1000 + l];
    wls[l] = s;
    mx = fmaxf(mx, s);
  }
#pragma unroll
  for (int off = 32; off > 0; off >>= 1) mx = fmaxf(mx, __shfl_xor(mx, off));
  if (lane == 0) red[wid] = mx;
  __syncthreads();
  if (tid == 0) {
    float m2 = red[0];
#pragma unroll
    for (int i = 1; i < 8; ++i) m2 = fmaxf(m2, red[i]);
    sh_scalar = m2;
  }
  __syncthreads();
  mx = sh_scalar;
  float sum = 0.f;
  for (int l = tid; l < 1000; l += 512) {
    float p = __expf(wls[l] - mx);
    wls[l] = p;
    sum += p;
  }
#pragma unroll
  for (int off = 32; off > 0; off >>= 1) sum += __shfl_xor(sum, off);
  if (lane == 0) red[wid] = sum;
  __syncthreads();
  if (tid == 0) {
    float s2 = red[0];
#pragma unroll
    for (int i = 1; i < 8; ++i) s2 += red[i];
    sh_scalar = s2;
  }
  __syncthreads();
  float inv = 1.f / sh_scalar;
  int dirr = tid >> 8, hh = tid & 255;
  float acc = 0.f;
  const bf16_t* lp = H + (size_t)65536 + (size_t)dirr * 32768 + b * 256 + hh; // l=0 slab=1
#pragma unroll 4
  for (int l = 0; l < 1000; ++l) acc += wls[l] * (float)lp[(size_t)l * 65536];
  dec_in[b * 1024 + tid] = (bf16_t)(acc * inv);
  dec_in[b * 1024 + 512 + tid] = hd_new[b * 512 + tid];
}

// fc relu + out sigmoid
__global__ void __launch_bounds__(256) k_fc_out(const bf16_t* __restrict__ dec_in,
                                                const float* __restrict__ fc_w,
                                                const float* __restrict__ fc_b,
                                                const float* __restrict__ out_w,
                                                const float* __restrict__ out_b,
                                                float* __restrict__ out) {
  int b = blockIdx.x;
  int tid = threadIdx.x;
  __shared__ float ctxs[512], zs[512], parts[32][8];
  for (int jj = tid; jj < 512; jj += 256) ctxs[jj] = (float)dec_in[b * 1024 + jj];
  __syncthreads();
  for (int n = tid; n < 512; n += 256) {
    float acc = fc_b[n];
    const float* wr = fc_w + n * 512;
    for (int k = 0; k < 512; ++k) acc += ctxs[k] * wr[k];
    zs[n] = fmaxf(acc, 0.f);
  }
  __syncthreads();
  int col = tid & 7, part = tid >> 3;
  float acc = 0.f;
  const float* wo = out_w + col * 512;
  for (int k = part * 16; k < part * 16 + 16; ++k) acc += zs[k] * wo[k];
  parts[part][col] = acc;
  __syncthreads();
  if (tid < 8) {
    float a = out_b[tid];
    for (int p2 = 0; p2 < 32; ++p2) a += parts[p2][tid];
    out[b * 8 + tid] = 1.f / (1.f + __expf(-a));
  }
}

// ---------------------------------------------------------------------------
extern "C" void kernel_launch(void* const* d_in, const int* in_sizes, int n_in,
                              void* d_out, int out_size, void* d_ws, size_t ws_size,
                              hipStream_t stream) {
  const int*   x       = (const int*)d_in[0];
  const float* embed_w = (const float*)d_in[1];
  const float* cw[6]   = {(const float*)d_in[2], (const float*)d_in[4], (const float*)d_in[6],
                          (const float*)d_in[8], (const float*)d_in[10], (const float*)d_in[12]};
  const float* cb[6]   = {(const float*)d_in[3], (const float*)d_in[5], (const float*)d_in[7],
                          (const float*)d_in[9], (const float*)d_in[11], (const float*)d_in[13]};
  const float* conv2_w = (const float*)d_in[14];
  const float* conv2_b = (const float*)d_in[15];
  const float* lstm_wif = (const float*)d_in[16];
  const float* lstm_whf = (const float*)d_in[17];
  const float* lstm_bif = (const float*)d_in[18];
  const float* lstm_bhf = (const float*)d_in[19];
  const float* lstm_wir = (const float*)d_in[20];
  const float* lstm_whr = (const float*)d_in[21];
  const float* lstm_bir = (const float*)d_in[22];
  const float* lstm_bhr = (const float*)d_in[23];
  const float* dec_wi  = (const float*)d_in[24];
  const float* dec_wh  = (const float*)d_in[25];
  const float* dec_bi  = (const float*)d_in[26];
  const float* dec_bh  = (const float*)d_in[27];
  const float* attn_v  = (const float*)d_in[28];
  const float* we_w    = (const float*)d_in[29];
  const float* we_b    = (const float*)d_in[30];
  const float* wd_w    = (const float*)d_in[31];
  const float* wd_b    = (const float*)d_in[32];
  const float* fc_w    = (const float*)d_in[33];
  const float* fc_b    = (const float*)d_in[34];
  const float* out_w   = (const float*)d_in[35];
  const float* out_b   = (const float*)d_in[36];
  const float* c0      = (const float*)d_in[37];
  float* out = (float*)d_out;

  // ---- workspace layout with lifetime overlays ----
  // Region R (71,905,792 B): [feat1p 30.78M][seq 32.77M][embp 8.36M]
  //   all dead before k_eenc -> e_enc (65.54M) overlays R at offset 0.
  char* base = (char*)d_ws;
  bf16_t* feat1p  = (bf16_t*)(base + 0);                 // 30,781,952 B
  bf16_t* seq     = (bf16_t*)(base + 30781952);          // 32,768,000 B
  bf16_t* embp    = (bf16_t*)(base + 63549952);          //  8,355,840 B
  bf16_t* e_enc   = (bf16_t*)(base + 0);                 // 65,536,000 B (overlay)
  char* p = base + 71905792;                             // end of region R
  auto alloc = [&](size_t bytes) { char* r = p; p += (bytes + 255) & ~(size_t)255; return r; };
  bf16_t* H       = (bf16_t*)alloc((size_t)1002 * 65536 * 2);  // h-history == lstm_out
  bf16_t* Wl      = (bf16_t*)alloc((size_t)2 * 1024 * 384 * 2);
  float*  bl      = (float*)alloc(2048 * 4);
  bf16_t* Wc1     = (bf16_t*)alloc(55296 * 2);
  float*  cbias   = (float*)alloc(512);
  bf16_t* Wc2     = (bf16_t*)alloc(49152 * 2);
  bf16_t* Wdec    = (bf16_t*)alloc((size_t)2048 * 1024 * 2);
  float*  bdec    = (float*)alloc(2048 * 4);
  bf16_t* Wwe     = (bf16_t*)alloc(131072 * 2);
  bf16_t* Wwd     = (bf16_t*)alloc(131072 * 2);
  unsigned* bar   = (unsigned*)alloc(512 * 4);
  bf16_t* dec_in  = (bf16_t*)alloc(131072 * 2);
  bf16_t* hd_new  = (bf16_t*)alloc(65536 * 2);
  float*  cd      = (float*)alloc(65536 * 4);
  float*  d_t     = (float*)alloc(32768 * 4);
  float*  scores  = (float*)alloc(128000 * 4);
  (void)ws_size; (void)n_in; (void)in_sizes; (void)out_size;

  k_init<<<1148, 256, 0, stream>>>(H, bar, feat1p, cd, dec_in, cbias, c0,
                                   cb[0], cb[1], cb[2], cb[3], cb[4], cb[5]);
  k_prep_lstm<<<2048, 128, 0, stream>>>(lstm_wif, lstm_whf, lstm_bif, lstm_bhf,
                                        lstm_wir, lstm_whr, lstm_bir, lstm_bhr, Wl, bl);
  k_prep_dec<<<2048, 256, 0, stream>>>(dec_wi, dec_wh, dec_bi, dec_bh, Wdec, bdec);
  k_prep_misc<<<1432, 256, 0, stream>>>(cw[0], cw[1], cw[2], cw[3], cw[4], cw[5],
                                        conv2_w, we_w, wd_w, Wc1, Wc2, Wwe, Wwd);
  k_embed<<<16320, 256, 0, stream>>>(x, embed_w, embp);
  k_conv1<<<dim3(1000, 6), 256, 0, stream>>>(embp, Wc1, cbias, feat1p);
  k_conv2<<<1000, 256, 0, stream>>>(feat1p, Wc2, conv2_b, seq);
  k_lstm<<<32, 256, 0, stream>>>(seq, Wl, bl, H, bar);
  k_eenc<<<dim3(1000, 4), 256, 0, stream>>>(H, Wwe, we_b, e_enc);
  for (int step = 0; step < 10; ++step) {
    k_dec_gates<<<32, 256, 0, stream>>>(dec_in, Wdec, bdec, cd, hd_new);
    k_d<<<4, 256, 0, stream>>>(hd_new, Wwd, wd_b, d_t);
    k_score<<<500, 256, 0, stream>>>(e_enc, d_t, attn_v, scores);
    k_softmax_ctx<<<128, 512, 0, stream>>>(scores, H, hd_new, dec_in);
  }
  k_fc_out<<<128, 256, 0, stream>>>(dec_in, fc_w, fc_b, out_w, out_b, out);
}